// Round 14
// baseline (2679.523 us; speedup 1.0000x reference)
//
#include <hip/hip_runtime.h>

namespace {

constexpr int Bb = 512, Tt = 512, Ff = 64, Hh = 128, Gg = 384;
constexpr int CH = 64, NCH = Tt / CH;
constexpr float SZ = -1.44269504f;   // z/r/dense pre-scale (-log2 e)
constexpr float SN =  2.88539008f;   // n pre-scale (2 log2 e)

using short8  = __attribute__((ext_vector_type(8))) short;
using short4v = __attribute__((ext_vector_type(4))) short;
using f32x4   = __attribute__((ext_vector_type(4))) float;

__device__ __forceinline__ short f2bf(float f) {
  unsigned u = __float_as_uint(f);
  u += 0x7FFFu + ((u >> 16) & 1u);
  return (short)(u >> 16);
}
__device__ __forceinline__ float bf2f(short s) {
  return __uint_as_float(((unsigned)(unsigned short)s) << 16);
}

// ---------------------------------------------------------------------------
// prep: fp32 weights -> bf16 MFMA B-fragment images, gate-constants folded in.
// ---------------------------------------------------------------------------
__global__ __launch_bounds__(512, 4) void prep(const float* __restrict__ Wx0,
                                               const float* __restrict__ Wxr,
                                               const float* __restrict__ Wh,
                                               const float* __restrict__ Wd,
                                               char* __restrict__ WhF,
                                               char* __restrict__ WxF,
                                               char* __restrict__ WdF) {
  const int id = blockIdx.x * 512 + threadIdx.x;
  const int lane = id & 63, lr = lane & 15, lk = lane >> 4;
  const int q = id >> 6;
  const float* src; int col, ldn, row0; char* dst; float sc;
  if (q < 288) {         // WhF
    const int l = q / 96, rem = q % 96, w = rem / 12, f = rem % 12;
    const int g = f >> 2, ks = f & 3;
    src = Wh + (size_t)l * Hh * Gg; ldn = Gg;
    col = g * 128 + w * 16 + lr; row0 = ks * 32 + lk * 8;
    dst = WhF + (size_t)(q * 64 + lane) * 16;
    sc = (g < 2) ? SZ : SN;
  } else if (q < 528) {  // WxF
    int p = q - 288; int base;
    if (p < 48)       { src = Wx0; base = 0; }
    else if (p < 144) { src = Wxr; base = 48; p -= 48; }
    else              { src = Wxr + (size_t)Hh * Gg; base = 144; p -= 144; }
    int ct, ks;
    if (base == 0) { ct = p >> 1; ks = p & 1; } else { ct = p >> 2; ks = p & 3; }
    ldn = Gg; col = ct * 16 + lr; row0 = ks * 32 + lk * 8;
    dst = WxF + (size_t)((base + p) * 64 + lane) * 16;
    sc = (ct < 16) ? SZ : SN;
  } else {               // WdF
    const int p = q - 528;
    const int ct = p >> 2, ks = p & 3;
    src = Wd; ldn = Hh; col = ct * 16 + lr; row0 = ks * 32 + lk * 8;
    dst = WdF + (size_t)(p * 64 + lane) * 16;
    sc = SZ;
  }
  short8 v;
#pragma unroll
  for (int j = 0; j < 8; ++j) v[j] = f2bf(src[(size_t)(row0 + j) * ldn + col] * sc);
  *(short8*)dst = v;
}

// ---------------------------------------------------------------------------
// Phase G: gx for one team's 16 batch rows x 64 t x 384 cols (8 waves).
// ---------------------------------------------------------------------------
template <int KS>
__device__ void gemm_phase(const void* __restrict__ src, int t0,
                           const char* __restrict__ wxf,
                           const float* __restrict__ bias,
                           char* __restrict__ gx,
                           int rb, int w, int lane, int lr, int lk) {
  short8 bw[3][KS];
  float bs[3];
#pragma unroll
  for (int c = 0; c < 3; ++c) {
    const int ct = w * 3 + c;
    bs[c] = bias[ct * 16 + lr] * (ct < 16 ? SZ : SN);
#pragma unroll
    for (int ks = 0; ks < KS; ++ks)
      bw[c][ks] = *(const short8*)(wxf + (size_t)((ct * KS + ks) * 64 + lane) * 16);
  }
#pragma unroll 2
  for (int t = 0; t < CH; ++t) {
    short8 af[KS];
    if constexpr (KS == 2) {
      const float* xr = (const float*)src;
#pragma unroll
      for (int ks = 0; ks < 2; ++ks) {
        const float* p = xr + ((size_t)(rb * 16 + lr) * Tt + t0 + t) * Ff + ks * 32 + lk * 8;
        f32x4 u0 = *(const f32x4*)p, u1 = *(const f32x4*)(p + 4);
        short8 v;
#pragma unroll
        for (int j = 0; j < 4; ++j) { v[j] = f2bf(u0[j]); v[4 + j] = f2bf(u1[j]); }
        af[ks] = v;
      }
    } else {
      const char* hr = (const char*)src;
#pragma unroll
      for (int ks = 0; ks < 4; ++ks)
        af[ks] = *(const short8*)(hr + ((size_t)t * 512 + rb * 16 + lr) * 256 +
                                  ((ks * 64 + lk * 16) ^ ((lr & 7) << 4)));
    }
#pragma unroll
    for (int c = 0; c < 3; ++c) {
      f32x4 acc = {0.f, 0.f, 0.f, 0.f};
#pragma unroll
      for (int ks = 0; ks < KS; ++ks)
        acc = __builtin_amdgcn_mfma_f32_16x16x32_bf16(af[ks], bw[c][ks], acc, 0, 0, 0);
      const int ct = w * 3 + c;
      short4v o;
#pragma unroll
      for (int i = 0; i < 4; ++i) o[i] = f2bf(acc[i] + bs[c]);
      *(short4v*)(gx + (size_t)((t * 32 + rb) * 8 + (ct & 7)) * 1536 + lane * 24 + (ct >> 3) * 8) = o;
    }
  }
}

// ---------------------------------------------------------------------------
// Phase S: 64-step scan, R12 structure (team-private LDS flag sync, no
// s_barrier in-loop). Called per 8-wave team with team-local ltid/hb/cnt.
// ---------------------------------------------------------------------------
__device__ void scan_phase(const char* __restrict__ gx,
                           const char* __restrict__ whf,
                           short* __restrict__ hstream,
                           float* __restrict__ state, int t0, int dense,
                           const char* __restrict__ wdf,
                           const float* __restrict__ bdp,
                           float* __restrict__ out,
                           int rb, int ltid, char* hb, int* cnt) {
  const int w = ltid >> 6, lane = ltid & 63, lr = lane & 15, lk = lane >> 4;
  const int col = w * 16 + lr;

  short8 bwh[3][4];
#pragma unroll
  for (int g = 0; g < 3; ++g)
#pragma unroll
    for (int ks = 0; ks < 4; ++ks)
      bwh[g][ks] = *(const short8*)(whf + (size_t)((w * 12 + g * 4 + ks) * 64 + lane) * 16);

  short8 bwd[4]; float bdv = 0.f;
  if (dense) {
#pragma unroll
    for (int ks = 0; ks < 4; ++ks)
      bwd[ks] = *(const short8*)(wdf + (size_t)((w * 4 + ks) * 64 + lane) * 16);
    bdv = bdp[col] * SZ;
  }

  int hoffs[4];
#pragma unroll
  for (int i = 0; i < 4; ++i) {
    const int row = lk * 4 + i;
    hoffs[i] = row * 256 + ((col * 2) ^ ((row & 7) << 4));
  }

  if (ltid == 0) *cnt = 0;

  float hreg[4];
  if (t0 == 0) {
#pragma unroll
    for (int i = 0; i < 4; ++i) hreg[i] = 0.f;
    short* hz = (short*)hb;
    for (int i = ltid; i < 2048; i += 512) hz[i] = 0;
  } else {
    f32x4 s = *(const f32x4*)(state + (size_t)(rb * 512 + ltid) * 4);
#pragma unroll
    for (int i = 0; i < 4; ++i) {
      hreg[i] = s[i];
      *(short*)(hb + hoffs[i]) = f2bf(s[i]);
    }
  }

  const char* gp = gx + (size_t)(rb * 8 + w) * 1536 + lane * 24;
  short4v pf0[3], pf1[3], pf2[3], pf3[3];
#pragma unroll
  for (int j = 0; j < 3; ++j) pf0[j] = *(const short4v*)(gp + j * 8);
#pragma unroll
  for (int j = 0; j < 3; ++j) pf1[j] = *(const short4v*)(gp + 393216 + j * 8);
  __syncthreads();   // WG-wide prologue sync (both teams reach exactly once)

  auto WAIT = [&](int target) {
    int budget = 1 << 22;   // bail (visible wrong result) instead of hang
    while (__hip_atomic_load(cnt, __ATOMIC_RELAXED, __HIP_MEMORY_SCOPE_WORKGROUP) < target &&
           --budget) {}
    __builtin_amdgcn_sched_barrier(0);   // pin: no ds_read hoisted above poll
  };

  auto STEP = [&](int s, short4v (&use)[3], short4v (&fill)[3]) {
    const int pin = s & 1;
    const char* hsrc = hb + pin * 4096;
    char* const hdst = hb + (1 - pin) * 4096;
    const int tg = t0 + s;

    if (s > 0) {
      WAIT(8 * s);
      if (!dense) {   // stream h(tg-1): buffer complete after poll
        short4v hv = *(const short4v*)(hsrc + ltid * 8);
        *(short4v*)(hstream + ((size_t)(s - 1) * 512 + rb * 16 + (ltid >> 5)) * 128 +
                    (ltid & 31) * 4) = hv;
      }
    }

    short8 ah[4];
#pragma unroll
    for (int ks = 0; ks < 4; ++ks)
      ah[ks] = *(const short8*)(hsrc + lr * 256 + ((ks * 64 + lk * 16) ^ ((lr & 7) << 4)));

    f32x4 aZ = {0.f, 0.f, 0.f, 0.f}, aR = aZ, aHn = aZ;
#pragma unroll
    for (int ks = 0; ks < 4; ++ks) {
      aZ  = __builtin_amdgcn_mfma_f32_16x16x32_bf16(ah[ks], bwh[0][ks], aZ, 0, 0, 0);
      aR  = __builtin_amdgcn_mfma_f32_16x16x32_bf16(ah[ks], bwh[1][ks], aR, 0, 0, 0);
      aHn = __builtin_amdgcn_mfma_f32_16x16x32_bf16(ah[ks], bwh[2][ks], aHn, 0, 0, 0);
    }
    if (s + 2 < CH) {
      const char* p = gp + (size_t)(s + 2) * 393216;
      fill[0] = *(const short4v*)p;
      fill[1] = *(const short4v*)(p + 8);
      fill[2] = *(const short4v*)(p + 16);
    }
    if (dense && tg > 0) {
      f32x4 aD = {0.f, 0.f, 0.f, 0.f};
#pragma unroll
      for (int ks = 0; ks < 4; ++ks)
        aD = __builtin_amdgcn_mfma_f32_16x16x32_bf16(ah[ks], bwd[ks], aD, 0, 0, 0);
#pragma unroll
      for (int i = 0; i < 4; ++i)
        out[((size_t)(rb * 16 + lk * 4 + i) * Tt + (tg - 1)) * Hh + col] =
            __builtin_amdgcn_rcpf(1.f + __builtin_amdgcn_exp2f(aD[i] + bdv));
    }

    float hn4[4];
#pragma unroll
    for (int i = 0; i < 4; ++i) {
      const float z  = __builtin_amdgcn_rcpf(1.f + __builtin_amdgcn_exp2f(aZ[i] + bf2f(use[0][i])));
      const float rr = __builtin_amdgcn_rcpf(1.f + __builtin_amdgcn_exp2f(aR[i] + bf2f(use[1][i])));
      const float eu = __builtin_amdgcn_exp2f(__builtin_fmaf(rr, aHn[i], bf2f(use[2][i])));
      const float nn = __builtin_fmaf(-2.f, __builtin_amdgcn_rcpf(1.f + eu), 1.f);
      const float h  = __builtin_fmaf(z, hreg[i] - nn, nn);
      hn4[i] = h; hreg[i] = h;
    }
    unsigned p01, p23;
    asm("v_cvt_pk_bf16_f32 %0, %1, %2" : "=v"(p01) : "v"(hn4[0]), "v"(hn4[1]));
    asm("v_cvt_pk_bf16_f32 %0, %1, %2" : "=v"(p23) : "v"(hn4[2]), "v"(hn4[3]));
    *(short*)(hdst + hoffs[0]) = (short)(p01 & 0xffffu);
    *(short*)(hdst + hoffs[1]) = (short)(p01 >> 16);
    *(short*)(hdst + hoffs[2]) = (short)(p23 & 0xffffu);
    *(short*)(hdst + hoffs[3]) = (short)(p23 >> 16);

    // publish: this wave's LDS ops retired -> ONE flag increment per wave
    __builtin_amdgcn_sched_barrier(0);
    asm volatile("s_waitcnt lgkmcnt(0)");
    __builtin_amdgcn_sched_barrier(0);
    if (lane == 0) atomicAdd(cnt, 1);
    __builtin_amdgcn_sched_barrier(0);
  };

  for (int tb = 0; tb < CH; tb += 4) {
    STEP(tb + 0, pf0, pf2);
    STEP(tb + 1, pf1, pf3);
    STEP(tb + 2, pf2, pf0);
    STEP(tb + 3, pf3, pf1);
  }

  WAIT(8 * CH);   // h(t0+CH-1) complete in buf[0] (CH even)

  {
    f32x4 sv;
#pragma unroll
    for (int i = 0; i < 4; ++i) sv[i] = hreg[i];
    *(f32x4*)(state + (size_t)(rb * 512 + ltid) * 4) = sv;
  }
  if (!dense) {
    short4v hv = *(const short4v*)(hb + ltid * 8);
    *(short4v*)(hstream + ((size_t)(CH - 1) * 512 + rb * 16 + (ltid >> 5)) * 128 +
                (ltid & 31) * 4) = hv;
  } else if (t0 + CH == Tt) {
    short8 ah[4];
#pragma unroll
    for (int ks = 0; ks < 4; ++ks)
      ah[ks] = *(const short8*)(hb + lr * 256 + ((ks * 64 + lk * 16) ^ ((lr & 7) << 4)));
    f32x4 aD = {0.f, 0.f, 0.f, 0.f};
#pragma unroll
    for (int ks = 0; ks < 4; ++ks)
      aD = __builtin_amdgcn_mfma_f32_16x16x32_bf16(ah[ks], bwd[ks], aD, 0, 0, 0);
#pragma unroll
    for (int i = 0; i < 4; ++i)
      out[((size_t)(rb * 16 + lk * 4 + i) * Tt + (Tt - 1)) * Hh + col] =
          __builtin_amdgcn_rcpf(1.f + __builtin_amdgcn_exp2f(aD[i] + bdv));
  }
}

struct LArgs {
  const void* src; const char* wxf; const char* whf; const float* bias;
  char* gx; short* hstream; float* state; int t0; int ksx; int dense;
};

// 1024-thread WG = 2 independent 8-wave teams (rb pair), team-private flag
// sync -> each SIMD hosts 2+2 waves at independently drifting phases.
__global__ __launch_bounds__(1024, 1) void fused(LArgs a0, LArgs a1, LArgs a2,
                                                 const char* __restrict__ wdf,
                                                 const float* __restrict__ bd,
                                                 float* __restrict__ out) {
  __shared__ char hb[2][8192];
  __shared__ int  cnt[2][16];   // 64B-strided per team
  const int g = blockIdx.x >> 4;
  LArgs a = (g == 0) ? a0 : (g == 1 ? a1 : a2);
  const int tid = threadIdx.x;
  const int team = tid >> 9;
  const int ltid = tid & 511;
  const int rb = (blockIdx.x & 15) * 2 + team;
  const int w = ltid >> 6, lane = ltid & 63, lr = lane & 15, lk = lane >> 4;

  if (a.ksx == 2) gemm_phase<2>(a.src, a.t0, a.wxf, a.bias, a.gx, rb, w, lane, lr, lk);
  else            gemm_phase<4>(a.src, a.t0, a.wxf, a.bias, a.gx, rb, w, lane, lr, lk);

  // transition: gx stores drained once per chunk (WG-wide, both teams)
  __builtin_amdgcn_sched_barrier(0);
  asm volatile("s_waitcnt vmcnt(0)");
  __builtin_amdgcn_s_barrier();
  __builtin_amdgcn_sched_barrier(0);

  scan_phase(a.gx, a.whf, a.hstream, a.state, a.t0, a.dense, wdf, bd, out,
             rb, ltid, hb[team], &cnt[team][0]);
}

}  // namespace

extern "C" void kernel_launch(void* const* d_in, const int* in_sizes, int n_in,
                              void* d_out, int out_size, void* d_ws, size_t ws_size,
                              hipStream_t stream) {
  const float* x   = (const float*)d_in[0];   // [B,T,F]
  const float* Wx0 = (const float*)d_in[1];
  const float* Wxr = (const float*)d_in[2];
  const float* Wh  = (const float*)d_in[3];
  const float* b   = (const float*)d_in[4];
  const float* Wd  = (const float*)d_in[5];
  const float* bd  = (const float*)d_in[6];
  float* out = (float*)d_out;

  char* ws = (char*)d_ws;
  char*  WhF    = ws;                              // 294912
  char*  WxF    = ws + 294912;                     // 245760
  char*  WdF    = ws + 540672;                     // 32768
  float* state0 = (float*)(ws + 573440);           // 3 x 262144
  char*  gx0    = ws + 1441792;                    // 3 x 25165824
  char*  gx1    = gx0 + 25165824;
  char*  gx2    = gx1 + 25165824;
  short* hc     = (short*)(ws + 76939264);         // 4 x 8388608 B: [l][parity]

  prep<<<70, 512, 0, stream>>>(Wx0, Wxr, Wh, Wd, WhF, WxF, WdF);

  const size_t WXOFF[3] = {0, 49152, 147456};
  for (int r = 0; r < NCH + 2; ++r) {
    LArgs la[3]; int n = 0;
    for (int l = 0; l < 3; ++l) {
      const int k = r - l;
      if (k < 0 || k >= NCH) continue;
      LArgs& A = la[n++];
      A.src = (l == 0) ? (const void*)x
                       : (const void*)(hc + (size_t)((l - 1) * 2 + (k & 1)) * 4194304);
      A.wxf = WxF + WXOFF[l];
      A.whf = WhF + (size_t)l * 98304;
      A.bias = b + l * Gg;
      A.gx = (l == 0) ? gx0 : (l == 1 ? gx1 : gx2);
      A.hstream = (l < 2) ? hc + (size_t)(l * 2 + (k & 1)) * 4194304 : nullptr;
      A.state = state0 + l * 65536;
      A.t0 = k * CH;
      A.ksx = (l == 0) ? 2 : 4;
      A.dense = (l == 2) ? 1 : 0;
    }
    for (int i = n; i < 3; ++i) la[i] = la[0];
    fused<<<n * 16, 1024, 0, stream>>>(la[0], la[1], la[2], WdF, bd, out);
  }
}

// Round 15
// 1150.818 us; speedup vs baseline: 2.3284x; 2.3284x over previous
//
#include <hip/hip_runtime.h>

namespace {

constexpr int Bb = 512, Tt = 512, Ff = 64, Hh = 128, Gg = 384;
constexpr int CH = 64;            // time-chunk length
constexpr int NCH = Tt / CH;      // 8 chunks

using short8  = __attribute__((ext_vector_type(8))) short;
using short4v = __attribute__((ext_vector_type(4))) short;
using f32x4   = __attribute__((ext_vector_type(4))) float;

__device__ __forceinline__ short f2bf(float f) {
  unsigned u = __float_as_uint(f);
  u += 0x7FFFu + ((u >> 16) & 1u);   // round-to-nearest-even
  return (short)(u >> 16);
}
__device__ __forceinline__ float bf2f(short s) {
  return __uint_as_float(((unsigned)(unsigned short)s) << 16);
}
__device__ __forceinline__ float sigm(float x) { return 1.0f / (1.0f + __expf(-x)); }
__device__ __forceinline__ float tanh_fast(float x) { return 1.0f - 2.0f / (1.0f + __expf(2.0f * x)); }

__device__ __forceinline__ void gl_lds16(const char* g, char* l) {
  __builtin_amdgcn_global_load_lds((const __attribute__((address_space(1))) void*)g,
                                   (__attribute__((address_space(3))) void*)l, 16, 0, 0);
}

// ---------------------------------------------------------------------------
// prep: gather fp32 weights into bf16 MFMA fragment images (16B per lane).
// Same images serve as B-frags (old) or A-frags of W^T (swapped) — identical.
// ---------------------------------------------------------------------------
__global__ __launch_bounds__(512, 4) void prep(const float* __restrict__ Wx0,
                                               const float* __restrict__ Wxr,
                                               const float* __restrict__ Wh,
                                               const float* __restrict__ Wd,
                                               char* __restrict__ WhF,
                                               char* __restrict__ WxF,
                                               char* __restrict__ WdF) {
  const int id = blockIdx.x * 512 + threadIdx.x;
  const int lane = id & 63, lr = lane & 15, lk = lane >> 4;
  const int q = id >> 6;
  const float* src; int col, ldn, row0; char* dst;
  if (q < 288) {         // WhF
    const int l = q / 96, rem = q % 96, w = rem / 12, f = rem % 12;
    const int g = f >> 2, ks = f & 3;
    src = Wh + (size_t)l * Hh * Gg; ldn = Gg;
    col = g * 128 + w * 16 + lr; row0 = ks * 32 + lk * 8;
    dst = WhF + (size_t)(q * 64 + lane) * 16;
  } else if (q < 528) {  // WxF
    int p = q - 288; int base;
    if (p < 48)       { src = Wx0; base = 0; }
    else if (p < 144) { src = Wxr; base = 48; p -= 48; }
    else              { src = Wxr + (size_t)Hh * Gg; base = 144; p -= 144; }
    int ct, ks;
    if (base == 0) { ct = p >> 1; ks = p & 1; } else { ct = p >> 2; ks = p & 3; }
    ldn = Gg; col = ct * 16 + lr; row0 = ks * 32 + lk * 8;
    dst = WxF + (size_t)((base + p) * 64 + lane) * 16;
  } else {               // WdF
    const int p = q - 528;
    const int ct = p >> 2, ks = p & 3;
    src = Wd; ldn = Hh; col = ct * 16 + lr; row0 = ks * 32 + lk * 8;
    dst = WdF + (size_t)(p * 64 + lane) * 16;
  }
  short8 v;
#pragma unroll
  for (int j = 0; j < 8; ++j) v[j] = f2bf(src[(size_t)(row0 + j) * ldn + col]);
  *(short8*)dst = v;
}

// ---------------------------------------------------------------------------
// gx chunk GEMM (SWAPPED operands): one WG = 64 rows (one t) x 384 cols.
// D = mfma(W-frag, act-frag): lane holds (batch row = lane&15, 4 consecutive
// gate cols = (lane>>4)*4+i). gx store addressing identical to before (the
// lane->(row,colgroup) map is unchanged); bias now per-reg (f32x4).
// ---------------------------------------------------------------------------
template <int KS>
__device__ void gemm_chunk(const void* __restrict__ src, int t0,
                           const char* __restrict__ wxf,
                           const float* __restrict__ bias,
                           char* __restrict__ gx, int wg, char* at) {
  constexpr int ROWB = KS * 64;   // bytes per A row
  const int tid = threadIdx.x;
  const int w = tid >> 6, lane = tid & 63, lr = lane & 15, lk = lane >> 4;
  const int trel = wg >> 3, b0 = (wg & 7) * 64;

  if constexpr (KS == 2) {
    const float* x = (const float*)src;
    const int row = tid >> 3, seg = tid & 7;
    const float* pr = x + ((size_t)(b0 + row) * Tt + t0 + trel) * Ff + seg * 8;
    f32x4 a = *(const f32x4*)pr, c = *(const f32x4*)(pr + 4);
    short8 o;
#pragma unroll
    for (int j = 0; j < 4; ++j) { o[j] = f2bf(a[j]); o[4 + j] = f2bf(c[j]); }
    *(short8*)(at + row * ROWB + ((seg * 16) ^ ((row & 7) << 4))) = o;
  } else {
    const char* h = (const char*)src + ((size_t)trel * 512 + b0) * ROWB;
    gl_lds16(h + tid * 16, at + tid * 16);
    gl_lds16(h + 8192 + tid * 16, at + 8192 + tid * 16);
    asm volatile("s_waitcnt vmcnt(0)");
  }
  __syncthreads();

  short8 bw[3][KS];
  f32x4 bs4[3];
#pragma unroll
  for (int c = 0; c < 3; ++c) {
    const int ct = w * 3 + c;
    bs4[c] = *(const f32x4*)(bias + ct * 16 + lk * 4);
#pragma unroll
    for (int ks = 0; ks < KS; ++ks)
      bw[c][ks] = *(const short8*)(wxf + (size_t)((ct * KS + ks) * 64 + lane) * 16);
  }

#pragma unroll
  for (int rt = 0; rt < 4; ++rt) {
    const int row = rt * 16 + lr;
    short8 aa[KS];
#pragma unroll
    for (int ks = 0; ks < KS; ++ks)
      aa[ks] = *(const short8*)(at + row * ROWB + ((ks * 64 + lk * 16) ^ ((row & 7) << 4)));
#pragma unroll
    for (int c = 0; c < 3; ++c) {
      f32x4 acc = {0.f, 0.f, 0.f, 0.f};
#pragma unroll
      for (int ks = 0; ks < KS; ++ks)
        acc = __builtin_amdgcn_mfma_f32_16x16x32_bf16(bw[c][ks], aa[ks], acc, 0, 0, 0);
      const int ct = w * 3 + c;
      short4v o;
#pragma unroll
      for (int i = 0; i < 4; ++i) o[i] = f2bf(acc[i] + bs4[c][i]);
      const int rb = (b0 >> 4) + rt;
      *(short4v*)(gx + (size_t)((trel * 32 + rb) * 8 + (ct & 7)) * 1536 + lane * 24 + (ct >> 3) * 8) = o;
    }
  }
}

// ---------------------------------------------------------------------------
// GRU scan over one time chunk (SWAPPED operands). One WG = 16 batch rows,
// 8 waves x 16 hidden cols. Lane holds (row lr, cols w*16+lk*4..+3) -> the
// h-write is ONE ds_write_b64 (was 4 scattered ds_write_b16): shortest
// possible write+drain leg before the step barrier.
// ---------------------------------------------------------------------------
template <bool DENSE>
__device__ void scan_chunk(const char* __restrict__ gx,
                           const char* __restrict__ whf,
                           short* __restrict__ hstream,
                           float* __restrict__ state, int t0,
                           const char* __restrict__ wdf,
                           const float* __restrict__ bdp,
                           float* __restrict__ out, int rb,
                           char* h_buf, float* ob) {
  const int tid = threadIdx.x;
  const int w = tid >> 6, lane = tid & 63, lr = lane & 15, lk = lane >> 4;

  short8 bwh[3][4];
#pragma unroll
  for (int g = 0; g < 3; ++g)
#pragma unroll
    for (int ks = 0; ks < 4; ++ks)
      bwh[g][ks] = *(const short8*)(whf + (size_t)((w * 12 + g * 4 + ks) * 64 + lane) * 16);

  short8 bwd[4];
  f32x4 bd4 = {0.f, 0.f, 0.f, 0.f};
  if constexpr (DENSE) {
#pragma unroll
    for (int ks = 0; ks < 4; ++ks)
      bwd[ks] = *(const short8*)(wdf + (size_t)((w * 4 + ks) * 64 + lane) * 16);
    bd4 = *(const f32x4*)(bdp + w * 16 + lk * 4);
  }

  // this thread's h slot: row lr, cols w*16+lk*4..+3 (8B, swizzled row image)
  const int hoff = lr * 256 + (((w * 16 + lk * 4) * 2) ^ ((lr & 7) << 4));

  float hreg[4];
  if (t0 == 0) {
#pragma unroll
    for (int i = 0; i < 4; ++i) hreg[i] = 0.f;
    short* hz = (short*)h_buf;
    for (int i = tid; i < 2048; i += 512) hz[i] = 0;
  } else {
    f32x4 s = *(const f32x4*)(state + (size_t)(rb * 512 + tid) * 4);
    short4v sv;
#pragma unroll
    for (int i = 0; i < 4; ++i) { hreg[i] = s[i]; sv[i] = f2bf(s[i]); }
    *(short4v*)(h_buf + hoff) = sv;
  }

  auto issue = [&](int trel, short4v* d) {
    const char* p = gx + (size_t)((trel * 32 + rb) * 8 + w) * 1536 + lane * 24;
    d[0] = *(const short4v*)p;
    d[1] = *(const short4v*)(p + 8);
    d[2] = *(const short4v*)(p + 16);
  };
  short4v pfA[3], pfB[3];
  issue(0, pfA);
  issue(1, pfB);
  __syncthreads();

  auto step = [&](int t, short4v* cur) {
    const int pp = t & 1;
    char* const hsrc = h_buf + pp * 4096;
    char* const hdst = h_buf + (1 - pp) * 4096;

    // snapshot this step's gx BEFORE the prefetch reuses the buffer
    const short4v g0 = cur[0], g1 = cur[1], g2 = cur[2];

    short8 ah[4];
#pragma unroll
    for (int ks = 0; ks < 4; ++ks)
      ah[ks] = *(const short8*)(hsrc + lr * 256 + ((ks * 64 + lk * 16) ^ ((lr & 7) << 4)));

    f32x4 aZ = {0.f, 0.f, 0.f, 0.f}, aR = aZ, aHn = aZ;
#pragma unroll
    for (int ks = 0; ks < 4; ++ks) {
      aZ  = __builtin_amdgcn_mfma_f32_16x16x32_bf16(bwh[0][ks], ah[ks], aZ, 0, 0, 0);
      aR  = __builtin_amdgcn_mfma_f32_16x16x32_bf16(bwh[1][ks], ah[ks], aR, 0, 0, 0);
      aHn = __builtin_amdgcn_mfma_f32_16x16x32_bf16(bwh[2][ks], ah[ks], aHn, 0, 0, 0);
    }
    if (t + 2 < t0 + CH) issue(t + 2 - t0, cur);

    if constexpr (DENSE) {
      if (t > 0) {
        f32x4 aD = {0.f, 0.f, 0.f, 0.f};
#pragma unroll
        for (int ks = 0; ks < 4; ++ks)
          aD = __builtin_amdgcn_mfma_f32_16x16x32_bf16(bwd[ks], ah[ks], aD, 0, 0, 0);
        f32x4 ov;
#pragma unroll
        for (int i = 0; i < 4; ++i) ov[i] = sigm(aD[i] + bd4[i]);
        *(f32x4*)(ob + pp * 2048 + lr * 128 + w * 16 + lk * 4) = ov;
      }
    }

    float hn4[4];
#pragma unroll
    for (int i = 0; i < 4; ++i) {
      const float z = sigm(aZ[i] + bf2f(g0[i]));
      const float r = sigm(aR[i] + bf2f(g1[i]));
      const float n = tanh_fast(bf2f(g2[i]) + r * aHn[i]);
      const float h = z * hreg[i] + (1.f - z) * n;
      hreg[i] = h;
      hn4[i] = h;
    }
    unsigned p01, p23;
    asm("v_cvt_pk_bf16_f32 %0, %1, %2" : "=v"(p01) : "v"(hn4[0]), "v"(hn4[1]));
    asm("v_cvt_pk_bf16_f32 %0, %1, %2" : "=v"(p23) : "v"(hn4[2]), "v"(hn4[3]));
    const unsigned long long hv64 = ((unsigned long long)p23 << 32) | p01;
    *(unsigned long long*)(hdst + hoff) = hv64;   // ONE ds_write_b64

    __builtin_amdgcn_sched_barrier(0);
    asm volatile("s_waitcnt lgkmcnt(0)");
    __builtin_amdgcn_s_barrier();
    __builtin_amdgcn_sched_barrier(0);

    if constexpr (DENSE) {
      if (t > 0) {
        f32x4 v = *(const f32x4*)(ob + pp * 2048 + tid * 4);
        *(f32x4*)(out + ((size_t)(rb * 16 + (tid >> 5)) * Tt + (t - 1)) * Hh + (tid & 31) * 4) = v;
      }
    } else {
      short4v hv = *(const short4v*)(hdst + tid * 8);
      *(short4v*)(hstream + (size_t)((t - t0) * 512 + rb * 16 + (tid >> 5)) * 128 + (tid & 31) * 4) = hv;
    }
  };

  for (int tb = t0; tb < t0 + CH; tb += 2) {
    step(tb, pfA);
    step(tb + 1, pfB);
  }

  {  // save recurrent state for next chunk
    f32x4 sv;
#pragma unroll
    for (int i = 0; i < 4; ++i) sv[i] = hreg[i];
    *(f32x4*)(state + (size_t)(rb * 512 + tid) * 4) = sv;
  }

  if constexpr (DENSE) {
    if (t0 + CH == Tt) {   // emit final row t = Tt-1 from h(Tt-1) in h_buf[0]
      short8 ah[4];
#pragma unroll
      for (int ks = 0; ks < 4; ++ks)
        ah[ks] = *(const short8*)(h_buf + lr * 256 + ((ks * 64 + lk * 16) ^ ((lr & 7) << 4)));
      f32x4 aD = {0.f, 0.f, 0.f, 0.f};
#pragma unroll
      for (int ks = 0; ks < 4; ++ks)
        aD = __builtin_amdgcn_mfma_f32_16x16x32_bf16(bwd[ks], ah[ks], aD, 0, 0, 0);
      f32x4 ov;
#pragma unroll
      for (int i = 0; i < 4; ++i) ov[i] = sigm(aD[i] + bd4[i]);
      *(f32x4*)(out + ((size_t)(rb * 16 + lr) * Tt + (Tt - 1)) * Hh + w * 16 + lk * 4) = ov;
    }
  }
}

struct GArgs { const void* src; char* gx; const char* wxf; const float* bias; int t0; int isx; };
struct SArgs { const char* gx; short* hstream; float* state; const char* whf; int t0; int dense; };

__global__ __launch_bounds__(512, 1) void gemm_multi(GArgs a0, GArgs a1, GArgs a2) {
  __shared__ char at[16384];
  const int g = blockIdx.x >> 9;
  const int wg = blockIdx.x & 511;
  GArgs a = (g == 0) ? a0 : (g == 1 ? a1 : a2);
  if (a.isx) gemm_chunk<2>(a.src, a.t0, a.wxf, a.bias, a.gx, wg, at);
  else       gemm_chunk<4>(a.src, a.t0, a.wxf, a.bias, a.gx, wg, at);
}

__global__ __launch_bounds__(512, 1) void scan_multi(SArgs a0, SArgs a1, SArgs a2,
                                                     const char* __restrict__ wdf,
                                                     const float* __restrict__ bd,
                                                     float* __restrict__ out) {
  __shared__ char hb[8192];
  __shared__ float ob[4096];
  const int g = blockIdx.x >> 5;
  const int rb = blockIdx.x & 31;
  SArgs a = (g == 0) ? a0 : (g == 1 ? a1 : a2);
  if (a.dense) scan_chunk<true >(a.gx, a.whf, a.hstream, a.state, a.t0, wdf, bd, out, rb, hb, ob);
  else         scan_chunk<false>(a.gx, a.whf, a.hstream, a.state, a.t0, wdf, bd, out, rb, hb, ob);
}

}  // namespace

extern "C" void kernel_launch(void* const* d_in, const int* in_sizes, int n_in,
                              void* d_out, int out_size, void* d_ws, size_t ws_size,
                              hipStream_t stream) {
  const float* x   = (const float*)d_in[0];   // [B,T,F]
  const float* Wx0 = (const float*)d_in[1];   // [F,3H]
  const float* Wxr = (const float*)d_in[2];   // [L-1,H,3H]
  const float* Wh  = (const float*)d_in[3];   // [L,H,3H]
  const float* b   = (const float*)d_in[4];   // [L,3H]
  const float* Wd  = (const float*)d_in[5];   // [H,H]
  const float* bd  = (const float*)d_in[6];   // [H]
  float* out = (float*)d_out;

  char* ws = (char*)d_ws;
  char*  WhF   = ws;                               // 294912 B
  char*  WxF   = ws + 294912;                      // 245760 B
  char*  WdF   = ws + 540672;                      // 32768 B
  float* state0 = (float*)(ws + 573440);           // 3 x 262144 B
  float* state1 = state0 + 65536;
  float* state2 = state1 + 65536;
  char*  gx0 = ws + 2097152;                       // 3 x 25165824 B
  char*  gx1 = gx0 + 25165824;
  char*  gx2 = gx1 + 25165824;
  char*  hc  = ws + 2097152 + 3 * 25165824;        // 4 x 8388608 B: [l][parity]

  prep<<<70, 512, 0, stream>>>(Wx0, Wxr, Wh, Wd, WhF, WxF, WdF);

  const size_t WXOFF[3] = {0, 49152, 147456};
  for (int r = 0; r < NCH + 2; ++r) {
    GArgs ga[3]; SArgs sa[3]; int n = 0;
    for (int l = 0; l < 3; ++l) {
      const int k = r - l;
      if (k < 0 || k >= NCH) continue;
      const void* src = (l == 0) ? (const void*)x
                                 : (const void*)(hc + ((size_t)((l - 1) * 2 + (k & 1))) * 8388608);
      char*  gxl = (l == 0) ? gx0 : (l == 1 ? gx1 : gx2);
      float* st  = (l == 0) ? state0 : (l == 1 ? state1 : state2);
      ga[n] = { src, gxl, WxF + WXOFF[l], b + l * Gg, k * CH, l == 0 };
      sa[n] = { gxl, (l < 2) ? (short*)(hc + (size_t)(l * 2 + (k & 1)) * 8388608) : (short*)nullptr,
                st, WhF + (size_t)l * 98304, k * CH, l == 2 };
      ++n;
    }
    for (int i = n; i < 3; ++i) { ga[i] = ga[0]; sa[i] = sa[0]; }
    gemm_multi<<<n * 512, 512, 0, stream>>>(ga[0], ga[1], ga[2]);
    scan_multi<<<n * 32, 512, 0, stream>>>(sa[0], sa[1], sa[2], WdF, bd, out);
  }
}